// Round 10
// baseline (161.011 us; speedup 1.0000x reference)
//
#include <hip/hip_runtime.h>
#include <hip/hip_bf16.h>
#include <stdint.h>

#define NT 20000
#define DIM 1024
#define HID 512
#define DATT_N 256
#define NCLUS 10
#define NCLS_N 4
#define NBS 79        // ceil(NT/256) sort blocks
#define NRT2 313      // ceil(NT/64) row tiles

typedef __bf16 bf16;
typedef __attribute__((ext_vector_type(8))) __bf16 bf16x8;
typedef __attribute__((ext_vector_type(4))) float f32x4;

__device__ __forceinline__ void gload_lds16(const void* g, void* l) {
  __builtin_amdgcn_global_load_lds(
      (const __attribute__((address_space(1))) unsigned int*)g,
      (__attribute__((address_space(3))) unsigned int*)l, 16, 0, 0);
}

// ---------------- K1: setup = hist + zero_pool + W1/W2 transpose-cast ----------------

#define ZPB 20                       // zero blocks (NCLUS*HID/256)
#define TW1B (32 * 4 * NCLUS)        // 1280 W1-transpose blocks (32x128 tiles)
#define TW2B (16 * 4 * NCLUS)        // 640  W2-transpose blocks

// 32x128 tile transpose-cast: dst[b][j][i] = bf16(src[b][i][j])
__device__ __forceinline__ void tr_body(const float* __restrict__ s, bf16* __restrict__ d,
                                        int R, int Cc, int i0, int j0, float (*t)[128]) {
  int tid = threadIdx.x;
  int cr = tid >> 5;                 // 0..7
  int cc4 = (tid & 31) << 2;         // 0..124 step 4
#pragma unroll
  for (int yy = 0; yy < 32; yy += 8)
    *(f32x4*)&t[yy + cr][cc4] = *(const f32x4*)&s[(size_t)(i0 + yy + cr) * Cc + j0 + cc4];
  __syncthreads();
  int col = tid >> 1, h = (tid & 1) << 4;
  bf16 tmp[16];
#pragma unroll
  for (int k = 0; k < 16; ++k) tmp[k] = (bf16)t[h + k][col];
  *(bf16x8*)&d[(size_t)(j0 + col) * R + i0 + h] = *(bf16x8*)&tmp[0];
  *(bf16x8*)&d[(size_t)(j0 + col) * R + i0 + h + 8] = *(bf16x8*)&tmp[8];
}

__global__ __launch_bounds__(256) void setup_kernel(
    const int* __restrict__ cid, int* __restrict__ blkcnt, float* __restrict__ pool,
    const float* __restrict__ W1, bf16* __restrict__ w1t,
    const float* __restrict__ W2, bf16* __restrict__ w2t) {
  __shared__ float t[32][128];
  __shared__ int wcnt[4][16];
  int b = blockIdx.x;
  int tid = threadIdx.x;
  if (b < NBS) {
    int lane = tid & 63, w = tid >> 6;
    int n = b * 256 + tid;
    int mycid = (n < NT) ? cid[n] : -1;
#pragma unroll
    for (int c = 0; c < NCLUS; ++c) {
      unsigned long long m = __ballot(mycid == c);
      if (lane == c) wcnt[w][c] = __popcll(m);
    }
    __syncthreads();
    if (tid < NCLUS)
      blkcnt[b * NCLUS + tid] =
          wcnt[0][tid] + wcnt[1][tid] + wcnt[2][tid] + wcnt[3][tid];
  } else if (b < NBS + ZPB) {
    int i = (b - NBS) * 256 + tid;
    if (i < NCLUS * HID) pool[i] = 0.f;
  } else if (b < NBS + ZPB + TW1B) {
    int bb = b - NBS - ZPB;          // z*128 + rt*4 + ct ; R=DIM rows, Cc=HID cols
    int z = bb >> 7, r = bb & 127, rt = r >> 2, ct = r & 3;
    tr_body(W1 + (size_t)z * DIM * HID, w1t + (size_t)z * DIM * HID,
            DIM, HID, rt * 32, ct * 128, t);
  } else {
    int bb = b - NBS - ZPB - TW1B;   // z*64 + rt*4 + ct ; R=HID, Cc=HID
    int z = bb >> 6, r = bb & 63, rt = r >> 2, ct = r & 3;
    tr_body(W2 + (size_t)z * HID * HID, w2t + (size_t)z * HID * HID,
            HID, HID, rt * 32, ct * 128, t);
  }
}

// ---------------- K2: scatter with inlined prefix (block 0 publishes cnt/offs) ----------------

__global__ __launch_bounds__(256) void scatter_kernel(
    const int* __restrict__ cid, const int* __restrict__ blkcnt,
    int* __restrict__ cnt, int* __restrict__ offs, int* __restrict__ order) {
  __shared__ int sbase[16];
  __shared__ int scnt[16];
  __shared__ int soffs[16];
  __shared__ int wcnt[4][16];
  __shared__ int wbase[4][16];
  int tid = threadIdx.x;
  int lane = tid & 63, w = tid >> 6;
  int bx = blockIdx.x;
  if (tid < NCLUS) {
    int base = 0, run = 0;
    for (int b = 0; b < NBS; ++b) {
      int v = blkcnt[b * NCLUS + tid];
      if (b < bx) base += v;
      run += v;
    }
    sbase[tid] = base;
    scnt[tid] = run;
  }
  __syncthreads();
  if (tid == 0) {
    int a = 0;
    for (int i = 0; i < NCLUS; ++i) { soffs[i] = a; a += scnt[i]; }
    soffs[NCLUS] = a;
  }
  __syncthreads();
  if (bx == 0 && tid <= NCLUS) {
    if (tid < NCLUS) cnt[tid] = scnt[tid];
    offs[tid] = soffs[tid];
  }
  int n = bx * 256 + tid;
  int mycid = (n < NT) ? cid[n] : -1;
  unsigned long long lmask = (lane == 63) ? ~0ull >> 1 : (1ull << lane) - 1;
  int myrank = 0;
#pragma unroll
  for (int c = 0; c < NCLUS; ++c) {
    unsigned long long m = __ballot(mycid == c);
    if (mycid == c) myrank = __popcll(m & lmask);
    if (lane == c) wcnt[w][c] = __popcll(m);
  }
  __syncthreads();
  if (tid < NCLUS) {
    int pre = sbase[tid];
#pragma unroll
    for (int ww = 0; ww < 4; ++ww) { wbase[ww][tid] = pre; pre += wcnt[ww][tid]; }
  }
  __syncthreads();
  if (n < NT) order[soffs[mycid] + wbase[w][mycid] + myrank] = n;
}

// XCD-grouping decode
__device__ __forceinline__ bool decode_grp2(int d, int& c, int& rt, int& j) {
  int x8 = d & 7, s = d >> 3;
  int g = (s >> 2) * 8 + x8;
  if (g >= NRT2 * NCLUS) return false;
  j = s & 3;
  c = g / NRT2;
  rt = g - c * NRT2;
  return true;
}

// ---------------- GEMM1: h1 = relu(x[order] @ W1[c]^T + b1[c]) ----------------
// Counted-vmcnt pipeline (T4): B double-buffered via global_load_lds issued one
// K-step ahead; raw s_barrier + lgkmcnt(0) only (no vmcnt drain). A reg-staged:
// fp32 global -> reg (issued under prior MFMA) -> cvt bf16 -> swizzled ds_write.

__global__ __launch_bounds__(128, 2) void gemm1_kernel(
    const float* __restrict__ x, const int* __restrict__ order,
    const bf16* __restrict__ w1t, const float* __restrict__ b1,
    const int* __restrict__ offs, const int* __restrict__ cnt, bf16* __restrict__ h1) {
  int c, rt, j;
  if (!decode_grp2(blockIdx.x, c, rt, j)) return;
  int cntc = cnt[c];
  int row0 = rt * 64;
  if (row0 >= cntc) return;
  int seg = offs[c];
  int n0 = j * 128;

  __shared__ bf16 Als[64 * 64];      // [row][slot-swizzled k], bf16
  __shared__ bf16 Bls[2][128 * 64];  // double-buffered B
  __shared__ int s_ord[64];

  int tid = threadIdx.x;
  int lane = tid & 63, w = tid >> 6;
  if (tid < 64) {
    int ar = seg + row0 + tid; if (ar > NT - 1) ar = NT - 1;
    s_ord[tid] = order[ar];
  }
  __syncthreads();

  int rx = lane & 7, hi = lane >> 4;
  int kswz = ((lane & 7) ^ (lane >> 3)) << 3;     // B source swizzle (16B slots)

  // B staging ptrs: 16 chunks of 8 rows x 64 k (bf16)
  const bf16* bptr[8]; int boff[8];
#pragma unroll
  for (int i = 0; i < 8; ++i) {
    int ch = i * 2 + w;
    int r = ch * 8 + (lane >> 3);
    bptr[i] = w1t + (size_t)(c * HID + n0 + r) * DIM + kswz;
    boff[i] = ch * 512;
  }
  // A reg-stage ptr: thread covers row r=tid>>1, f32 cols [h*32, h*32+32)
  int arow = tid >> 1, ah = tid & 1;
  const float* fa = x + (size_t)s_ord[arow] * DIM + ah * 32;

  f32x4 acc[2][8];
#pragma unroll
  for (int m = 0; m < 2; m++)
#pragma unroll
    for (int n = 0; n < 8; n++) acc[m][n] = {0.f, 0.f, 0.f, 0.f};

  // prologue: B(0) gloads FIRST (so A(0)-reg wait implies B(0) done), then A(0) regs
#pragma unroll
  for (int i = 0; i < 8; ++i) gload_lds16(bptr[i], &Bls[0][boff[i]]);
  f32x4 areg[8];
#pragma unroll
  for (int i = 0; i < 8; ++i) areg[i] = *(const f32x4*)(fa + i * 4);

  const int NKT = DIM / 64;
#pragma unroll 2
  for (int t = 0; t < NKT; ++t) {
    // issue B(t+1) into other buffer (stays in flight across this step's MFMA)
    if (t + 1 < NKT) {
#pragma unroll
      for (int i = 0; i < 8; ++i)
        gload_lds16(bptr[i] + (t + 1) * 64, &Bls[(t + 1) & 1][boff[i]]);
    }
    // cvt + swizzled ds_write of A(t)  (compiler waits areg's vmcnt -> B(t) done too)
#pragma unroll
    for (int i = 0; i < 4; ++i) {
      f32x4 u = areg[2 * i], v = areg[2 * i + 1];
      bf16x8 tb;
      tb[0] = (bf16)u[0]; tb[1] = (bf16)u[1]; tb[2] = (bf16)u[2]; tb[3] = (bf16)u[3];
      tb[4] = (bf16)v[0]; tb[5] = (bf16)v[1]; tb[6] = (bf16)v[2]; tb[7] = (bf16)v[3];
      int s = ah * 4 + i;
      *(bf16x8*)&Als[arow * 64 + (((s ^ (arow & 7)) << 3))] = tb;
    }
    asm volatile("s_waitcnt lgkmcnt(0)" ::: "memory");  // my ds_writes visible
    __builtin_amdgcn_s_barrier();                       // tile t fully staged
    asm volatile("" ::: "memory");

    // fragment reads
    bf16x8 a[2][2], b[2][8];
    const bf16* Bb = &Bls[t & 1][0];
#pragma unroll
    for (int ks = 0; ks < 2; ++ks) {
      int t16 = ks * 4 + hi;
      int ko = ((t16 ^ rx) << 3);
#pragma unroll
      for (int m = 0; m < 2; m++)
        a[ks][m] = *(const bf16x8*)(&Als[(w * 32 + m * 16 + (lane & 15)) * 64 + ko]);
#pragma unroll
      for (int n = 0; n < 8; n++)
        b[ks][n] = *(const bf16x8*)(&Bb[(n * 16 + (lane & 15)) * 64 + ko]);
    }
    // A(t+1) reg loads — hidden under MFMA
    if (t + 1 < NKT) {
#pragma unroll
      for (int i = 0; i < 8; ++i) areg[i] = *(const f32x4*)(fa + (t + 1) * 64 + i * 4);
    }
#pragma unroll
    for (int ks = 0; ks < 2; ++ks)
#pragma unroll
      for (int m = 0; m < 2; m++)
#pragma unroll
        for (int n = 0; n < 8; n++)
          acc[m][n] = __builtin_amdgcn_mfma_f32_16x16x32_bf16(a[ks][m], b[ks][n], acc[m][n], 0, 0, 0);
    asm volatile("" ::: "memory");
    __builtin_amdgcn_s_barrier();                       // reads done; next iter may overwrite
    asm volatile("" ::: "memory");
  }

  int valid = cntc - row0; if (valid > 64) valid = 64;
#pragma unroll
  for (int n = 0; n < 8; n++) {
    int col = n0 + n * 16 + (lane & 15);
    float bias = b1[c * HID + col];
#pragma unroll
    for (int m = 0; m < 2; m++) {
      int rbase = w * 32 + m * 16 + ((lane >> 4) << 2);
#pragma unroll
      for (int e = 0; e < 4; e++) {
        int r = rbase + e;
        if (r < valid) {
          float v = acc[m][n][e] + bias;
          h1[(size_t)(seg + row0 + r) * HID + col] = (bf16)(v > 0.f ? v : 0.f);
        }
      }
    }
  }
}

// ---------------- GEMM2: pool[c] += colsum(relu(h1 @ W2[c]^T + b2[c])) ----------------

__global__ __launch_bounds__(128, 3) void gemm2_kernel(
    const bf16* __restrict__ h1, const bf16* __restrict__ w2t, const float* __restrict__ b2,
    const int* __restrict__ offs, const int* __restrict__ cnt, float* __restrict__ pool) {
  int c, rt, j;
  if (!decode_grp2(blockIdx.x, c, rt, j)) return;
  int cntc = cnt[c];
  int row0 = rt * 64;
  if (row0 >= cntc) return;
  int seg = offs[c];
  int n0 = j * 128;
  int valid = cntc - row0; if (valid > 64) valid = 64;

  __shared__ bf16 Als[64 * 64];
  __shared__ bf16 Bls[128 * 64];

  int tid = threadIdx.x;
  int lane = tid & 63, w = tid >> 6;
  int rx = lane & 7, hi = lane >> 4;
  int kswz = ((lane & 7) ^ (lane >> 3)) << 3;

  const bf16* aptr[4]; int aoff[4];
  const bf16* bptr[8]; int boff[8];
#pragma unroll
  for (int i = 0; i < 4; ++i) {
    int ch = i * 2 + w;
    int r = ch * 8 + (lane >> 3);
    int ar = seg + row0 + r; if (ar > NT - 1) ar = NT - 1;
    aptr[i] = h1 + (size_t)ar * HID + kswz;
    aoff[i] = ch * 512;
  }
#pragma unroll
  for (int i = 0; i < 8; ++i) {
    int ch = i * 2 + w;
    int r = ch * 8 + (lane >> 3);
    bptr[i] = w2t + (size_t)(c * HID + n0 + r) * HID + kswz;
    boff[i] = ch * 512;
  }

  f32x4 acc[2][8];
#pragma unroll
  for (int m = 0; m < 2; m++)
#pragma unroll
    for (int n = 0; n < 8; n++) acc[m][n] = {0.f, 0.f, 0.f, 0.f};

  for (int k0 = 0; k0 < HID; k0 += 64) {
#pragma unroll
    for (int i = 0; i < 4; ++i) gload_lds16(aptr[i] + k0, &Als[aoff[i]]);
#pragma unroll
    for (int i = 0; i < 8; ++i) gload_lds16(bptr[i] + k0, &Bls[boff[i]]);
    __syncthreads();
#pragma unroll
    for (int ks = 0; ks < 2; ++ks) {
      int t16 = ks * 4 + hi;
      int ko = ((t16 ^ rx) << 3);
      bf16x8 a[2], b[8];
#pragma unroll
      for (int m = 0; m < 2; m++)
        a[m] = *(const bf16x8*)(&Als[(w * 32 + m * 16 + (lane & 15)) * 64 + ko]);
#pragma unroll
      for (int n = 0; n < 8; n++)
        b[n] = *(const bf16x8*)(&Bls[(n * 16 + (lane & 15)) * 64 + ko]);
#pragma unroll
      for (int m = 0; m < 2; m++)
#pragma unroll
        for (int n = 0; n < 8; n++)
          acc[m][n] = __builtin_amdgcn_mfma_f32_16x16x32_bf16(a[m], b[n], acc[m][n], 0, 0, 0);
    }
    __syncthreads();
  }

#pragma unroll
  for (int n = 0; n < 8; n++) {
    int col = n0 + n * 16 + (lane & 15);
    float bias = b2[c * HID + col];
    float s = 0.f;
#pragma unroll
    for (int m = 0; m < 2; m++) {
      int rbase = w * 32 + m * 16 + ((lane >> 4) << 2);
#pragma unroll
      for (int e = 0; e < 4; e++) {
        if (rbase + e < valid) {
          float v = acc[m][n][e] + bias;
          s += (v > 0.f ? v : 0.f);
        }
      }
    }
    s += __shfl_xor(s, 16);
    s += __shfl_xor(s, 32);
    if (lane < 16) atomicAdd(&pool[c * HID + col], s);
  }
}

// ---------------- tails (fp32, parallelized; R7 structure) ----------------

__global__ __launch_bounds__(256) void tail_fc(
    const float* __restrict__ pool, const int* __restrict__ cnt,
    const float* __restrict__ fcW, const float* __restrict__ fcb,
    float* __restrict__ hbuf) {
  int c = blockIdx.x >> 3;
  int jt = blockIdx.x & 7;
  __shared__ float hc[HID];
  __shared__ float red[4][64];
  int tid = threadIdx.x;
  float inv = 1.f / fmaxf((float)cnt[c], 1.f);
  for (int k = tid; k < HID; k += 256) hc[k] = pool[c * HID + k] * inv;
  __syncthreads();
  int jl = tid & 63, kg = tid >> 6;
  int j = jt * 64 + jl;
  float s = 0.f;
#pragma unroll 4
  for (int k = kg * 128; k < kg * 128 + 128; ++k) s += hc[k] * fcW[(size_t)k * HID + j];
  red[kg][jl] = s;
  __syncthreads();
  if (kg == 0) {
    float v = red[0][jl] + red[1][jl] + red[2][jl] + red[3][jl] + fcb[j];
    hbuf[c * HID + j] = fmaxf(v, 0.f);
  }
}

__global__ __launch_bounds__(1024) void tail_att(
    const float* __restrict__ hbuf,
    const float* __restrict__ Wa, const float* __restrict__ ba,
    const float* __restrict__ Wb, const float* __restrict__ bb,
    const float* __restrict__ Wc, const float* __restrict__ bc,
    float* __restrict__ score) {
  int c = blockIdx.x;
  __shared__ float h[HID];
  __shared__ float ra[4][DATT_N];
  __shared__ float rb[4][DATT_N];
  __shared__ float sc[DATT_N];
  int tid = threadIdx.x;
  for (int k = tid; k < HID; k += 1024) h[k] = hbuf[c * HID + k];
  __syncthreads();
  int jl = tid & 255, kg = tid >> 8;
  float sa = 0.f, sb = 0.f;
#pragma unroll 4
  for (int k = kg * 128; k < kg * 128 + 128; ++k) {
    float hv = h[k];
    sa += hv * Wa[(size_t)k * DATT_N + jl];
    sb += hv * Wb[(size_t)k * DATT_N + jl];
  }
  ra[kg][jl] = sa;
  rb[kg][jl] = sb;
  __syncthreads();
  if (kg == 0) {
    float va = ra[0][jl] + ra[1][jl] + ra[2][jl] + ra[3][jl] + ba[jl];
    float vb = rb[0][jl] + rb[1][jl] + rb[2][jl] + rb[3][jl] + bb[jl];
    float av = tanhf(va);
    float bv = 1.f / (1.f + expf(-vb));
    sc[jl] = av * bv * Wc[jl];
  }
  __syncthreads();
  for (int s2 = 128; s2 > 0; s2 >>= 1) {
    if (tid < s2) sc[tid] += sc[tid + s2];
    __syncthreads();
  }
  if (tid == 0) score[c] = sc[0] + bc[0];
}

__global__ __launch_bounds__(1024) void tail_fin(
    const float* __restrict__ score, const float* __restrict__ hbuf,
    const float* __restrict__ rhoW, const float* __restrict__ rhob,
    const float* __restrict__ clsW, const float* __restrict__ clsb,
    float* __restrict__ out) {
  __shared__ float Asm[NCLUS];
  __shared__ float hp[HID];
  __shared__ float rr[4][DATT_N];
  __shared__ float hr[DATT_N];
  __shared__ float lg[NCLS_N];
  int tid = threadIdx.x;
  if (tid == 0) {
    float mx = -1e30f;
    for (int c = 0; c < NCLUS; c++) mx = fmaxf(mx, score[c]);
    float sum = 0.f, e[NCLUS];
    for (int c = 0; c < NCLUS; c++) { e[c] = expf(score[c] - mx); sum += e[c]; }
    for (int c = 0; c < NCLUS; c++) Asm[c] = e[c] / sum;
  }
  __syncthreads();
  if (tid < HID) {
    float s = 0.f;
#pragma unroll
    for (int c = 0; c < NCLUS; c++) s += Asm[c] * hbuf[c * HID + tid];
    hp[tid] = s;
  }
  __syncthreads();
  int jl = tid & 255, kg = tid >> 8;
  float s = 0.f;
#pragma unroll 4
  for (int k = kg * 128; k < kg * 128 + 128; ++k) s += hp[k] * rhoW[(size_t)k * DATT_N + jl];
  rr[kg][jl] = s;
  __syncthreads();
  if (kg == 0) hr[jl] = fmaxf(rr[0][jl] + rr[1][jl] + rr[2][jl] + rr[3][jl] + rhob[jl], 0.f);
  __syncthreads();
  if (tid < NCLS_N * 64) {
    int t = tid >> 6, l = tid & 63;
    float cs = 0.f;
    for (int j = l; j < DATT_N; j += 64) cs += hr[j] * clsW[j * NCLS_N + t];
#pragma unroll
    for (int w = 32; w > 0; w >>= 1) cs += __shfl_xor(cs, w);
    if (l == 0) lg[t] = cs + clsb[t];
  }
  __syncthreads();
  if (tid == 0) {
    float mx = lg[0];
    int am = 0;
    for (int t = 1; t < NCLS_N; t++) if (lg[t] > mx) { mx = lg[t]; am = t; }
    float sum = 0.f, e[NCLS_N];
    for (int t = 0; t < NCLS_N; t++) { e[t] = expf(lg[t] - mx); sum += e[t]; }
    for (int t = 0; t < NCLS_N; t++) {
      out[t] = lg[t];
      out[NCLS_N + t] = e[t] / sum;
    }
    out[2 * NCLS_N] = (float)am;
  }
}

// ---------------- launch ----------------

extern "C" void kernel_launch(void* const* d_in, const int* in_sizes, int n_in,
                              void* d_out, int out_size, void* d_ws, size_t ws_size,
                              hipStream_t stream) {
  const float* x    = (const float*)d_in[0];
  const int*   cid  = (const int*)d_in[1];
  const float* W1   = (const float*)d_in[2];
  const float* b1   = (const float*)d_in[3];
  const float* W2   = (const float*)d_in[4];
  const float* b2   = (const float*)d_in[5];
  const float* fcW  = (const float*)d_in[6];
  const float* fcb  = (const float*)d_in[7];
  const float* Wa   = (const float*)d_in[8];
  const float* ba   = (const float*)d_in[9];
  const float* Wb   = (const float*)d_in[10];
  const float* bb   = (const float*)d_in[11];
  const float* Wc   = (const float*)d_in[12];
  const float* bc   = (const float*)d_in[13];
  const float* rhoW = (const float*)d_in[14];
  const float* rhob = (const float*)d_in[15];
  const float* clsW = (const float*)d_in[16];
  const float* clsb = (const float*)d_in[17];
  float* out = (float*)d_out;

  char* ws = (char*)d_ws;
  int*   cnt     = (int*)(ws + 0);
  int*   offs    = (int*)(ws + 64);
  float* score   = (float*)(ws + 128);
  int*   blkcnt  = (int*)(ws + 256);                    // NBS*NCLUS = 790 ints
  int*   order   = (int*)(ws + 256 + 4096);             // NT ints
  float* pool    = (float*)(ws + 256 + 4096 + 80000);
  float* hbuf    = (float*)(ws + 256 + 4096 + 80000 + NCLUS * HID * 4);
  size_t o = 256 + 4096 + 80000 + 2ull * NCLUS * HID * 4;
  o = (o + 255) & ~(size_t)255;
  bf16* w1t = (bf16*)(ws + o); o += (size_t)NCLUS * HID * DIM * 2;
  bf16* w2t = (bf16*)(ws + o); o += (size_t)NCLUS * HID * HID * 2;
  bf16* h1  = (bf16*)(ws + o); o += (size_t)NT * HID * 2;

  setup_kernel<<<dim3(NBS + ZPB + TW1B + TW2B), dim3(256), 0, stream>>>(
      cid, blkcnt, pool, W1, w1t, W2, w2t);
  scatter_kernel<<<dim3(NBS), dim3(256), 0, stream>>>(cid, blkcnt, cnt, offs, order);

  int nblk = 8 * ((NRT2 * NCLUS + 7) / 8) * 4;   // 12544
  gemm1_kernel<<<dim3(nblk), dim3(128), 0, stream>>>(x, order, w1t, b1, offs, cnt, h1);
  gemm2_kernel<<<dim3(nblk), dim3(128), 0, stream>>>(h1, w2t, b2, offs, cnt, pool);

  tail_fc<<<dim3(NCLUS * 8), dim3(256), 0, stream>>>(pool, cnt, fcW, fcb, hbuf);
  tail_att<<<dim3(NCLUS), dim3(1024), 0, stream>>>(hbuf, Wa, ba, Wb, bb, Wc, bc, score);
  tail_fin<<<dim3(1), dim3(1024), 0, stream>>>(score, hbuf, rhoW, rhob, clsW, clsb, out);
}

// Round 11
// 128.429 us; speedup vs baseline: 1.2537x; 1.2537x over previous
//
#include <hip/hip_runtime.h>
#include <hip/hip_bf16.h>
#include <stdint.h>

#define NT 20000
#define DIM 1024
#define HID 512
#define DATT_N 256
#define NCLUS 10
#define NCLS_N 4
#define NBS 79        // ceil(NT/256) sort blocks
#define NRT 157       // ceil(NT/128) row tiles

typedef __bf16 bf16;
typedef __attribute__((ext_vector_type(8))) __bf16 bf16x8;
typedef __attribute__((ext_vector_type(4))) float f32x4;

__device__ __forceinline__ void gload_lds16(const void* g, void* l) {
  __builtin_amdgcn_global_load_lds(
      (const __attribute__((address_space(1))) unsigned int*)g,
      (__attribute__((address_space(3))) unsigned int*)l, 16, 0, 0);
}

// ---------------- K1: setup = hist + zero_pool + W1/W2 transpose-cast ----------------

#define ZPB 20                       // zero blocks (NCLUS*HID/256)
#define TW1B (32 * 4 * NCLUS)        // 1280 W1-transpose blocks (32x128 tiles)
#define TW2B (16 * 4 * NCLUS)        // 640  W2-transpose blocks

// 32x128 tile transpose-cast: dst[b][j][i] = bf16(src[b][i][j])
__device__ __forceinline__ void tr_body(const float* __restrict__ s, bf16* __restrict__ d,
                                        int R, int Cc, int i0, int j0, float (*t)[128]) {
  int tid = threadIdx.x;
  int cr = tid >> 5;                 // 0..7
  int cc4 = (tid & 31) << 2;         // 0..124 step 4
#pragma unroll
  for (int yy = 0; yy < 32; yy += 8)
    *(f32x4*)&t[yy + cr][cc4] = *(const f32x4*)&s[(size_t)(i0 + yy + cr) * Cc + j0 + cc4];
  __syncthreads();
  int col = tid >> 1, h = (tid & 1) << 4;
  bf16 tmp[16];
#pragma unroll
  for (int k = 0; k < 16; ++k) tmp[k] = (bf16)t[h + k][col];
  *(bf16x8*)&d[(size_t)(j0 + col) * R + i0 + h] = *(bf16x8*)&tmp[0];
  *(bf16x8*)&d[(size_t)(j0 + col) * R + i0 + h + 8] = *(bf16x8*)&tmp[8];
}

__global__ __launch_bounds__(256) void setup_kernel(
    const int* __restrict__ cid, int* __restrict__ blkcnt, float* __restrict__ pool,
    const float* __restrict__ W1, bf16* __restrict__ w1t,
    const float* __restrict__ W2, bf16* __restrict__ w2t) {
  __shared__ float t[32][128];
  __shared__ int wcnt[4][16];
  int b = blockIdx.x;
  int tid = threadIdx.x;
  if (b < NBS) {
    int lane = tid & 63, w = tid >> 6;
    int n = b * 256 + tid;
    int mycid = (n < NT) ? cid[n] : -1;
#pragma unroll
    for (int c = 0; c < NCLUS; ++c) {
      unsigned long long m = __ballot(mycid == c);
      if (lane == c) wcnt[w][c] = __popcll(m);
    }
    __syncthreads();
    if (tid < NCLUS)
      blkcnt[b * NCLUS + tid] =
          wcnt[0][tid] + wcnt[1][tid] + wcnt[2][tid] + wcnt[3][tid];
  } else if (b < NBS + ZPB) {
    int i = (b - NBS) * 256 + tid;
    if (i < NCLUS * HID) pool[i] = 0.f;
  } else if (b < NBS + ZPB + TW1B) {
    int bb = b - NBS - ZPB;          // z*128 + rt*4 + ct ; R=DIM rows, Cc=HID cols
    int z = bb >> 7, r = bb & 127, rt = r >> 2, ct = r & 3;
    tr_body(W1 + (size_t)z * DIM * HID, w1t + (size_t)z * DIM * HID,
            DIM, HID, rt * 32, ct * 128, t);
  } else {
    int bb = b - NBS - ZPB - TW1B;   // z*64 + rt*4 + ct ; R=HID, Cc=HID
    int z = bb >> 6, r = bb & 63, rt = r >> 2, ct = r & 3;
    tr_body(W2 + (size_t)z * HID * HID, w2t + (size_t)z * HID * HID,
            HID, HID, rt * 32, ct * 128, t);
  }
}

// ---------------- K2: scatter with inlined prefix (block 0 publishes cnt/offs) ----------------

__global__ __launch_bounds__(256) void scatter_kernel(
    const int* __restrict__ cid, const int* __restrict__ blkcnt,
    int* __restrict__ cnt, int* __restrict__ offs, int* __restrict__ order) {
  __shared__ int sbase[16];
  __shared__ int scnt[16];
  __shared__ int soffs[16];
  __shared__ int wcnt[4][16];
  __shared__ int wbase[4][16];
  int tid = threadIdx.x;
  int lane = tid & 63, w = tid >> 6;
  int bx = blockIdx.x;
  if (tid < NCLUS) {
    int base = 0, run = 0;
    for (int b = 0; b < NBS; ++b) {
      int v = blkcnt[b * NCLUS + tid];
      if (b < bx) base += v;
      run += v;
    }
    sbase[tid] = base;
    scnt[tid] = run;
  }
  __syncthreads();
  if (tid == 0) {
    int a = 0;
    for (int i = 0; i < NCLUS; ++i) { soffs[i] = a; a += scnt[i]; }
    soffs[NCLUS] = a;
  }
  __syncthreads();
  if (bx == 0 && tid <= NCLUS) {
    if (tid < NCLUS) cnt[tid] = scnt[tid];
    offs[tid] = soffs[tid];
  }
  int n = bx * 256 + tid;
  int mycid = (n < NT) ? cid[n] : -1;
  unsigned long long lmask = (lane == 63) ? ~0ull >> 1 : (1ull << lane) - 1;
  int myrank = 0;
#pragma unroll
  for (int c = 0; c < NCLUS; ++c) {
    unsigned long long m = __ballot(mycid == c);
    if (mycid == c) myrank = __popcll(m & lmask);
    if (lane == c) wcnt[w][c] = __popcll(m);
  }
  __syncthreads();
  if (tid < NCLUS) {
    int pre = sbase[tid];
#pragma unroll
    for (int ww = 0; ww < 4; ++ww) { wbase[ww][tid] = pre; pre += wcnt[ww][tid]; }
  }
  __syncthreads();
  if (n < NT) order[soffs[mycid] + wbase[w][mycid] + myrank] = n;
}

// ---------------- K3: gather_cast: xs[i][:] = bf16(x[order[i]][:]) ----------------

__global__ void gather_cast(const float* __restrict__ x, const int* __restrict__ order,
                            bf16* __restrict__ xs) {
  int t = blockIdx.x * 256 + threadIdx.x;  // one thread per 8 elements
  int row = t >> 7;                        // 128 threads per row (1024 elems)
  if (row >= NT) return;
  int col = (t & 127) << 3;
  const f32x4* p = (const f32x4*)(x + (size_t)order[row] * DIM + col);
  f32x4 u = p[0], v = p[1];
  bf16x8 w;
  w[0] = (bf16)u[0]; w[1] = (bf16)u[1]; w[2] = (bf16)u[2]; w[3] = (bf16)u[3];
  w[4] = (bf16)v[0]; w[5] = (bf16)v[1]; w[6] = (bf16)v[2]; w[7] = (bf16)v[3];
  *(bf16x8*)(xs + (size_t)row * DIM + col) = w;
}

// XCD-grouping decode: the 4 n-blocks of one (cluster,row-tile) group get
// dispatch slots congruent mod 8 -> same XCD L2 serves the shared A panel.
__device__ __forceinline__ bool decode_grp(int d, int& c, int& rt, int& j) {
  int x8 = d & 7, s = d >> 3;
  int g = (s >> 2) * 8 + x8;
  if (g >= NRT * NCLUS) return false;
  j = s & 3;
  c = g / NRT;
  rt = g - c * NRT;
  return true;
}

// ---------------- GEMM1: h1 = relu(xs @ W1[c]^T + b1[c]) ----------------
// 128x128 tile, BK=64, 4 waves, T2 both-sides XOR swizzle (rule 21):
// source 16B-slot s of row r lands in LDS slot s (linear dest), but the lane
// fetches global slot s^(r&7); fragment reads XOR the same -> bank-balanced.

__global__ __launch_bounds__(256, 2) void gemm1_kernel(
    const bf16* __restrict__ xs, const bf16* __restrict__ w1t, const float* __restrict__ b1,
    const int* __restrict__ offs, const int* __restrict__ cnt, bf16* __restrict__ h1) {
  int c, rt, j;
  if (!decode_grp(blockIdx.x, c, rt, j)) return;
  int cntc = cnt[c];
  int row0 = rt * 128;
  if (row0 >= cntc) return;
  int seg = offs[c];
  int n0 = j * 128;

  __shared__ bf16 Als[128 * 64];  // [row][slot-swizzled k]
  __shared__ bf16 Bls[128 * 64];

  int tid = threadIdx.x;
  int lane = tid & 63, wid = tid >> 6;
  int wr = wid >> 1, wc = wid & 1;
  int rx = lane & 7, hi = lane >> 4;
  int kswz = ((lane & 7) ^ (lane >> 3)) << 3;   // source-swizzled 16B slot

  const bf16* aptr[4]; int aoff[4];
  const bf16* bptr[4]; int boff[4];
#pragma unroll
  for (int i = 0; i < 4; ++i) {
    int chunk = i * 4 + wid;              // 0..15, 8 rows x 64 k each
    int r = chunk * 8 + (lane >> 3);      // tile row 0..127
    int ar = seg + row0 + r; if (ar > NT - 1) ar = NT - 1;
    aptr[i] = xs + (size_t)ar * DIM + kswz;
    aoff[i] = chunk * 512;
    bptr[i] = w1t + (size_t)(c * HID + n0 + r) * DIM + kswz;
    boff[i] = chunk * 512;
  }

  f32x4 acc[4][4];
#pragma unroll
  for (int m = 0; m < 4; m++)
#pragma unroll
    for (int n = 0; n < 4; n++) acc[m][n] = {0.f, 0.f, 0.f, 0.f};

  for (int k0 = 0; k0 < DIM; k0 += 64) {
#pragma unroll
    for (int i = 0; i < 4; ++i) gload_lds16(aptr[i] + k0, &Als[aoff[i]]);
#pragma unroll
    for (int i = 0; i < 4; ++i) gload_lds16(bptr[i] + k0, &Bls[boff[i]]);
    __syncthreads();
#pragma unroll
    for (int ks = 0; ks < 2; ++ks) {
      int t16 = ks * 4 + hi;              // true 16B-slot index
      int ko = ((t16 ^ rx) << 3);         // swizzled read slot
      bf16x8 a[4], b[4];
#pragma unroll
      for (int m = 0; m < 4; m++)
        a[m] = *(const bf16x8*)(&Als[(wr * 64 + m * 16 + (lane & 15)) * 64 + ko]);
#pragma unroll
      for (int n = 0; n < 4; n++)
        b[n] = *(const bf16x8*)(&Bls[(wc * 64 + n * 16 + (lane & 15)) * 64 + ko]);
#pragma unroll
      for (int m = 0; m < 4; m++)
#pragma unroll
        for (int n = 0; n < 4; n++)
          acc[m][n] = __builtin_amdgcn_mfma_f32_16x16x32_bf16(a[m], b[n], acc[m][n], 0, 0, 0);
    }
    __syncthreads();
  }

  int valid = cntc - row0; if (valid > 128) valid = 128;
#pragma unroll
  for (int n = 0; n < 4; n++) {
    int col = n0 + wc * 64 + n * 16 + (lane & 15);
    float bias = b1[c * HID + col];
#pragma unroll
    for (int m = 0; m < 4; m++) {
      int rbase = wr * 64 + m * 16 + ((lane >> 4) << 2);
#pragma unroll
      for (int e = 0; e < 4; e++) {
        int r = rbase + e;
        if (r < valid) {
          float v = acc[m][n][e] + bias;
          h1[(size_t)(seg + row0 + r) * HID + col] = (bf16)(v > 0.f ? v : 0.f);
        }
      }
    }
  }
}

// ---------------- GEMM2: pool[c] += colsum(relu(h1 @ W2[c]^T + b2[c])) ----------------

__global__ __launch_bounds__(256, 2) void gemm2_kernel(
    const bf16* __restrict__ h1, const bf16* __restrict__ w2t, const float* __restrict__ b2,
    const int* __restrict__ offs, const int* __restrict__ cnt, float* __restrict__ pool) {
  int c, rt, j;
  if (!decode_grp(blockIdx.x, c, rt, j)) return;
  int cntc = cnt[c];
  int row0 = rt * 128;
  if (row0 >= cntc) return;
  int seg = offs[c];
  int n0 = j * 128;
  int valid = cntc - row0; if (valid > 128) valid = 128;

  __shared__ bf16 Als[128 * 64];
  __shared__ bf16 Bls[128 * 64];

  int tid = threadIdx.x;
  int lane = tid & 63, wid = tid >> 6;
  int wr = wid >> 1, wc = wid & 1;
  int rx = lane & 7, hi = lane >> 4;
  int kswz = ((lane & 7) ^ (lane >> 3)) << 3;

  const bf16* aptr[4]; int aoff[4];
  const bf16* bptr[4]; int boff[4];
#pragma unroll
  for (int i = 0; i < 4; ++i) {
    int chunk = i * 4 + wid;
    int r = chunk * 8 + (lane >> 3);
    int ar = seg + row0 + r; if (ar > NT - 1) ar = NT - 1;
    aptr[i] = h1 + (size_t)ar * HID + kswz;
    aoff[i] = chunk * 512;
    bptr[i] = w2t + (size_t)(c * HID + n0 + r) * HID + kswz;
    boff[i] = chunk * 512;
  }

  f32x4 acc[4][4];
#pragma unroll
  for (int m = 0; m < 4; m++)
#pragma unroll
    for (int n = 0; n < 4; n++) acc[m][n] = {0.f, 0.f, 0.f, 0.f};

  for (int k0 = 0; k0 < HID; k0 += 64) {
#pragma unroll
    for (int i = 0; i < 4; ++i) gload_lds16(aptr[i] + k0, &Als[aoff[i]]);
#pragma unroll
    for (int i = 0; i < 4; ++i) gload_lds16(bptr[i] + k0, &Bls[boff[i]]);
    __syncthreads();
#pragma unroll
    for (int ks = 0; ks < 2; ++ks) {
      int t16 = ks * 4 + hi;
      int ko = ((t16 ^ rx) << 3);
      bf16x8 a[4], b[4];
#pragma unroll
      for (int m = 0; m < 4; m++)
        a[m] = *(const bf16x8*)(&Als[(wr * 64 + m * 16 + (lane & 15)) * 64 + ko]);
#pragma unroll
      for (int n = 0; n < 4; n++)
        b[n] = *(const bf16x8*)(&Bls[(wc * 64 + n * 16 + (lane & 15)) * 64 + ko]);
#pragma unroll
      for (int m = 0; m < 4; m++)
#pragma unroll
        for (int n = 0; n < 4; n++)
          acc[m][n] = __builtin_amdgcn_mfma_f32_16x16x32_bf16(a[m], b[n], acc[m][n], 0, 0, 0);
    }
    __syncthreads();
  }

#pragma unroll
  for (int n = 0; n < 4; n++) {
    int col = n0 + wc * 64 + n * 16 + (lane & 15);
    float bias = b2[c * HID + col];
    float s = 0.f;
#pragma unroll
    for (int m = 0; m < 4; m++) {
      int rbase = wr * 64 + m * 16 + ((lane >> 4) << 2);
#pragma unroll
      for (int e = 0; e < 4; e++) {
        if (rbase + e < valid) {
          float v = acc[m][n][e] + bias;
          s += (v > 0.f ? v : 0.f);
        }
      }
    }
    s += __shfl_xor(s, 16);
    s += __shfl_xor(s, 32);
    if (lane < 16) atomicAdd(&pool[c * HID + n0 + wc * 64 + n * 16 + lane], s);
  }
}

// ---------------- tails (fp32, parallelized; R7 structure) ----------------

__global__ __launch_bounds__(256) void tail_fc(
    const float* __restrict__ pool, const int* __restrict__ cnt,
    const float* __restrict__ fcW, const float* __restrict__ fcb,
    float* __restrict__ hbuf) {
  int c = blockIdx.x >> 3;
  int jt = blockIdx.x & 7;
  __shared__ float hc[HID];
  __shared__ float red[4][64];
  int tid = threadIdx.x;
  float inv = 1.f / fmaxf((float)cnt[c], 1.f);
  for (int k = tid; k < HID; k += 256) hc[k] = pool[c * HID + k] * inv;
  __syncthreads();
  int jl = tid & 63, kg = tid >> 6;
  int j = jt * 64 + jl;
  float s = 0.f;
#pragma unroll 4
  for (int k = kg * 128; k < kg * 128 + 128; ++k) s += hc[k] * fcW[(size_t)k * HID + j];
  red[kg][jl] = s;
  __syncthreads();
  if (kg == 0) {
    float v = red[0][jl] + red[1][jl] + red[2][jl] + red[3][jl] + fcb[j];
    hbuf[c * HID + j] = fmaxf(v, 0.f);
  }
}

__global__ __launch_bounds__(1024) void tail_att(
    const float* __restrict__ hbuf,
    const float* __restrict__ Wa, const float* __restrict__ ba,
    const float* __restrict__ Wb, const float* __restrict__ bb,
    const float* __restrict__ Wc, const float* __restrict__ bc,
    float* __restrict__ score) {
  int c = blockIdx.x;
  __shared__ float h[HID];
  __shared__ float ra[4][DATT_N];
  __shared__ float rb[4][DATT_N];
  __shared__ float sc[DATT_N];
  int tid = threadIdx.x;
  for (int k = tid; k < HID; k += 1024) h[k] = hbuf[c * HID + k];
  __syncthreads();
  int jl = tid & 255, kg = tid >> 8;
  float sa = 0.f, sb = 0.f;
#pragma unroll 4
  for (int k = kg * 128; k < kg * 128 + 128; ++k) {
    float hv = h[k];
    sa += hv * Wa[(size_t)k * DATT_N + jl];
    sb += hv * Wb[(size_t)k * DATT_N + jl];
  }
  ra[kg][jl] = sa;
  rb[kg][jl] = sb;
  __syncthreads();
  if (kg == 0) {
    float va = ra[0][jl] + ra[1][jl] + ra[2][jl] + ra[3][jl] + ba[jl];
    float vb = rb[0][jl] + rb[1][jl] + rb[2][jl] + rb[3][jl] + bb[jl];
    float av = tanhf(va);
    float bv = 1.f / (1.f + expf(-vb));
    sc[jl] = av * bv * Wc[jl];
  }
  __syncthreads();
  for (int s2 = 128; s2 > 0; s2 >>= 1) {
    if (tid < s2) sc[tid] += sc[tid + s2];
    __syncthreads();
  }
  if (tid == 0) score[c] = sc[0] + bc[0];
}

__global__ __launch_bounds__(1024) void tail_fin(
    const float* __restrict__ score, const float* __restrict__ hbuf,
    const float* __restrict__ rhoW, const float* __restrict__ rhob,
    const float* __restrict__ clsW, const float* __restrict__ clsb,
    float* __restrict__ out) {
  __shared__ float Asm[NCLUS];
  __shared__ float hp[HID];
  __shared__ float rr[4][DATT_N];
  __shared__ float hr[DATT_N];
  __shared__ float lg[NCLS_N];
  int tid = threadIdx.x;
  if (tid == 0) {
    float mx = -1e30f;
    for (int c = 0; c < NCLUS; c++) mx = fmaxf(mx, score[c]);
    float sum = 0.f, e[NCLUS];
    for (int c = 0; c < NCLUS; c++) { e[c] = expf(score[c] - mx); sum += e[c]; }
    for (int c = 0; c < NCLUS; c++) Asm[c] = e[c] / sum;
  }
  __syncthreads();
  if (tid < HID) {
    float s = 0.f;
#pragma unroll
    for (int c = 0; c < NCLUS; c++) s += Asm[c] * hbuf[c * HID + tid];
    hp[tid] = s;
  }
  __syncthreads();
  int jl = tid & 255, kg = tid >> 8;
  float s = 0.f;
#pragma unroll 4
  for (int k = kg * 128; k < kg * 128 + 128; ++k) s += hp[k] * rhoW[(size_t)k * DATT_N + jl];
  rr[kg][jl] = s;
  __syncthreads();
  if (kg == 0) hr[jl] = fmaxf(rr[0][jl] + rr[1][jl] + rr[2][jl] + rr[3][jl] + rhob[jl], 0.f);
  __syncthreads();
  if (tid < NCLS_N * 64) {
    int t = tid >> 6, l = tid & 63;
    float cs = 0.f;
    for (int j = l; j < DATT_N; j += 64) cs += hr[j] * clsW[j * NCLS_N + t];
#pragma unroll
    for (int w = 32; w > 0; w >>= 1) cs += __shfl_xor(cs, w);
    if (l == 0) lg[t] = cs + clsb[t];
  }
  __syncthreads();
  if (tid == 0) {
    float mx = lg[0];
    int am = 0;
    for (int t = 1; t < NCLS_N; t++) if (lg[t] > mx) { mx = lg[t]; am = t; }
    float sum = 0.f, e[NCLS_N];
    for (int t = 0; t < NCLS_N; t++) { e[t] = expf(lg[t] - mx); sum += e[t]; }
    for (int t = 0; t < NCLS_N; t++) {
      out[t] = lg[t];
      out[NCLS_N + t] = e[t] / sum;
    }
    out[2 * NCLS_N] = (float)am;
  }
}

// ---------------- launch ----------------

extern "C" void kernel_launch(void* const* d_in, const int* in_sizes, int n_in,
                              void* d_out, int out_size, void* d_ws, size_t ws_size,
                              hipStream_t stream) {
  const float* x    = (const float*)d_in[0];
  const int*   cid  = (const int*)d_in[1];
  const float* W1   = (const float*)d_in[2];
  const float* b1   = (const float*)d_in[3];
  const float* W2   = (const float*)d_in[4];
  const float* b2   = (const float*)d_in[5];
  const float* fcW  = (const float*)d_in[6];
  const float* fcb  = (const float*)d_in[7];
  const float* Wa   = (const float*)d_in[8];
  const float* ba   = (const float*)d_in[9];
  const float* Wb   = (const float*)d_in[10];
  const float* bb   = (const float*)d_in[11];
  const float* Wc   = (const float*)d_in[12];
  const float* bc   = (const float*)d_in[13];
  const float* rhoW = (const float*)d_in[14];
  const float* rhob = (const float*)d_in[15];
  const float* clsW = (const float*)d_in[16];
  const float* clsb = (const float*)d_in[17];
  float* out = (float*)d_out;

  char* ws = (char*)d_ws;
  int*   cnt     = (int*)(ws + 0);
  int*   offs    = (int*)(ws + 64);
  float* score   = (float*)(ws + 128);
  int*   blkcnt  = (int*)(ws + 256);                    // NBS*NCLUS = 790 ints
  int*   order   = (int*)(ws + 256 + 4096);             // NT ints
  float* pool    = (float*)(ws + 256 + 4096 + 80000);
  float* hbuf    = (float*)(ws + 256 + 4096 + 80000 + NCLUS * HID * 4);
  size_t o = 256 + 4096 + 80000 + 2ull * NCLUS * HID * 4;
  o = (o + 255) & ~(size_t)255;
  bf16* w1t = (bf16*)(ws + o); o += (size_t)NCLUS * HID * DIM * 2;
  bf16* w2t = (bf16*)(ws + o); o += (size_t)NCLUS * HID * HID * 2;
  bf16* h1  = (bf16*)(ws + o); o += (size_t)NT * HID * 2;
  bf16* xs  = (bf16*)(ws + o); o += (size_t)NT * DIM * 2;

  setup_kernel<<<dim3(NBS + ZPB + TW1B + TW2B), dim3(256), 0, stream>>>(
      cid, blkcnt, pool, W1, w1t, W2, w2t);
  scatter_kernel<<<dim3(NBS), dim3(256), 0, stream>>>(cid, blkcnt, cnt, offs, order);
  gather_cast<<<dim3(NT * 128 / 256), dim3(256), 0, stream>>>(x, order, xs);

  int nblk = 8 * ((NRT * NCLUS + 7) / 8) * 4;   // 6304
  gemm1_kernel<<<dim3(nblk), dim3(256), 0, stream>>>(xs, w1t, b1, offs, cnt, h1);
  gemm2_kernel<<<dim3(nblk), dim3(256), 0, stream>>>(h1, w2t, b2, offs, cnt, pool);

  tail_fc<<<dim3(NCLUS * 8), dim3(256), 0, stream>>>(pool, cnt, fcW, fcb, hbuf);
  tail_att<<<dim3(NCLUS), dim3(1024), 0, stream>>>(hbuf, Wa, ba, Wb, bb, Wc, bc, score);
  tail_fin<<<dim3(1), dim3(1024), 0, stream>>>(score, hbuf, rhoW, rhob, clsW, clsb, out);
}